// Round 7
// baseline (286.985 us; speedup 1.0000x reference)
//
#include <hip/hip_runtime.h>

// VQ: z [16384,512] f32, emb [8192,512] f32
// outputs (flat f32): z_q [8388608], loss [1], idx [16384], var [1]

#define BT   16384
#define DIMS 512
#define NE   8192
#define NS   8                       // n-splits
#define BN   128
#define NTPB (NE / NS / BN)          // n-tiles per block = 8
#define NSTEPS 128                   // NTPB * DIMS/32 flat K-steps (BK=32)

// out layout (float elements)
#define LOSS_OFF 8388608
#define IDX_OFF  8388609
#define V_OFF    8404993

// ws layout (bytes)
#define BEST_OFF  0         // u64[16384]
#define ENORM_OFF 131072    // f32[8192]
#define SUMS_OFF  163840    // double[3]
#define CNT_OFF   163864    // unsigned

typedef __attribute__((ext_vector_type(8))) short short8;
typedef __attribute__((ext_vector_type(4))) float floatx4;

#define AS1(p) ((const __attribute__((address_space(1))) void*)(p))
#define AS3(p) ((__attribute__((address_space(3))) void*)(p))

__device__ __forceinline__ unsigned f2bf(float f) {
    unsigned u = __builtin_bit_cast(unsigned, f);
    u += 0x7FFFu + ((u >> 16) & 1u);          // RNE
    return u >> 16;
}

// fused prep: emb->bf16 + ||e||^2 (blocks 0..NE/4), z->bf16 (rest), init best/sums/counter
__global__ __launch_bounds__(256) void prep_kernel(
    const float* __restrict__ z, const float* __restrict__ emb,
    ushort* __restrict__ zh, ushort* __restrict__ ehh,
    float* __restrict__ enorm, unsigned long long* __restrict__ best,
    double* __restrict__ sums, unsigned* __restrict__ counter)
{
    const int lane = threadIdx.x & 63, w = threadIdx.x >> 6;
    const int b = blockIdx.x;
    if (b < NE / 4) {
        const int row = b * 4 + w;
        const float4* p = (const float4*)(emb + (size_t)row * DIMS + lane * 8);
        float4 a = p[0], bb = p[1];
        uint4 h;
        h.x = f2bf(a.x) | (f2bf(a.y) << 16);
        h.y = f2bf(a.z) | (f2bf(a.w) << 16);
        h.z = f2bf(bb.x) | (f2bf(bb.y) << 16);
        h.w = f2bf(bb.z) | (f2bf(bb.w) << 16);
        *(uint4*)(ehh + (size_t)row * DIMS + lane * 8) = h;
        float s = a.x*a.x + a.y*a.y + a.z*a.z + a.w*a.w
                + bb.x*bb.x + bb.y*bb.y + bb.z*bb.z + bb.w*bb.w;
        #pragma unroll
        for (int off = 32; off > 0; off >>= 1) s += __shfl_down(s, off, 64);
        if (lane == 0) enorm[row] = s;
    } else {
        const int row = (b - NE / 4) * 4 + w;
        const float4* p = (const float4*)(z + (size_t)row * DIMS + lane * 8);
        float4 a = p[0], bb = p[1];
        uint4 h;
        h.x = f2bf(a.x) | (f2bf(a.y) << 16);
        h.y = f2bf(a.z) | (f2bf(a.w) << 16);
        h.z = f2bf(bb.x) | (f2bf(bb.y) << 16);
        h.w = f2bf(bb.z) | (f2bf(bb.w) << 16);
        *(uint4*)(zh + (size_t)row * DIMS + lane * 8) = h;
    }
    const int gid = b * 256 + threadIdx.x;
    if (gid < BT) best[gid] = 0xFFFFFFFFFFFFFFFFULL;
    if (gid == 0) { sums[0] = 0.0; sums[1] = 0.0; sums[2] = 0.0; *counter = 0u; }
}

// 256x128-tile 4-wave argmin GEMM, TWO independent blocks per CU.
// CHANGE vs R5/R6: R5's 8-wave lockstep block converges all waves at every
// barrier -> post-barrier the DS FIFO fills with all waves' read bursts
// before any MFMA is eligible; intra-wave interleave (R6) regressed.  The
// register file caps the CU at 8 waves of 256 regs (128 VGPR + 128 AGPR),
// so decorrelation must come from 2 co-resident 4-wave blocks with
// INDEPENDENT barrier domains: blocks drift into anti-phase, one block's
// MFMA covers the other's DS bursts (m97's "~3 blocks/CU implicit
// overlap" mechanism).  Geometry: BM=256 BN=128 BK=32, waves 4Mx1N (wave
// tile 64x128 -> same acc[4][8], same 48 frag VGPRs).  LDS 64 KB/block:
// A bufs x3 (16 KB: [256][32] ushorts) + B bufs x2 (8 KB: [128][32]).
// Swizzle: 4 chunks/row, phys = q ^ (row&3) — uniform 8 accesses per
// 16B LDS slot per wave b128 read (conflict-free, same principle as the
// proven 8-chunk scheme).  Step = R5's macro-burst schedule scaled:
// 12 reads (a0-3, b0-7) -> stage B(s+1)x2 + A(s+2)x4 -> LGK(7..0) x
// 8 CL4 clusters -> vmcnt(4) (A(s+2) rides) -> one barrier.  Triple-A
// rotation as R5.  Per-acc accumulation = same ascending-k sequence of
// K=32 MFMA chunks as BK=64's kk0/kk1 -> bitwise-identical scores,
// tie-break, absmax.  Grid 512 = 64 mt x 8 ns; ns = XCD so each XCD's
// 64 blocks share one 1 MB B-panel in its private L2.

#define DSR8O(dst, BASE, OFF) \
    asm volatile("ds_read_b128 %0, %1 offset:" #OFF : "=v"(dst) : "v"(BASE))

#define LGK(N_) do {                                                           \
    asm volatile("s_waitcnt lgkmcnt(" #N_ ")" ::: "memory");                   \
    __builtin_amdgcn_sched_barrier(0);                                         \
} while (0)

#define CL4(J_, BIDX_)                                                         \
    _Pragma("unroll")                                                          \
    for (int mi = 0; mi < 4; mi++)                                             \
        acc[mi][J_] = __builtin_amdgcn_mfma_f32_16x16x32_bf16(                 \
            a[mi], b[BIDX_], acc[mi][J_], 0, 0, 0);

// staging: one global_load_lds per call covers 16 rows (64 lanes x 16 B;
// lane l -> row l>>2, phys chunk l&3, pre-swizzled source chunk
// (l&3)^((l>>2)&3)).  Source step index clamped (tail steps re-load valid
// data into buffers never read again — branchless).
#define STAGE_A(SA_, H_, DST_) do {                                            \
    const int sc_ = (SA_) & (NSTEPS - 1);                                      \
    const int rb_ = ((H_) * 4 + w) * 16;                                       \
    const unsigned al_ = (DST_) + (unsigned)(rb_ * 32);                        \
    const ushort* g_ = zA + (size_t)rb_ * DIMS + soff + ((sc_ & 15) * 32);     \
    __builtin_amdgcn_global_load_lds(AS1(g_), AS3(&lds[al_]), 16, 0, 0);       \
} while (0)

#define STAGE_B(SB_, H_, DST_) do {                                            \
    const int sc_ = (SB_) & (NSTEPS - 1);                                      \
    const int rb_ = ((H_) * 4 + w) * 16;                                       \
    const unsigned bl_ = (DST_) + (unsigned)(rb_ * 32);                        \
    const ushort* g_ = eh + (size_t)(nsN + (sc_ >> 4) * BN + rb_) * DIMS       \
                     + soff + ((sc_ & 15) * 32);                               \
    __builtin_amdgcn_global_load_lds(AS1(g_), AS3(&lds[bl_]), 16, 0, 0);       \
} while (0)

// Per-step DS-queue schedule (in-order completion, per wave): 12 reads
// issued up front (r1-4 a0-3, r5-12 b0-7); cluster J needs a0-3 + b[J]
// = reads 1..5+J -> LGK(7-J).  Boundary: own in-flight = A(s+1)x4 (rode
// from s-1) + B(s+1)x2 + A(s+2)x4 = 10; vmcnt(4) retires the oldest 6
// (A(s+1), B(s+1)) and lets A(s+2) ride across the barrier.
// TM_: 0 -> vmcnt(4) boundary wait, 2 -> none (last step; epilogue drains)
#define STEP(S_, AR_, BR_, AW_, BW_, TM_) do {                                 \
    const int s_ = (S_);                                                       \
    short8 a[4], b[8];                                                         \
    const unsigned aV = ldsb + 2u * ((AR_) + aro + pxo);                       \
    const unsigned bV = ldsb + 2u * ((BR_) + bro + pxo);                       \
    DSR8O(a[0], aV, 0);    DSR8O(a[1], aV, 1024);                              \
    DSR8O(a[2], aV, 2048); DSR8O(a[3], aV, 3072);                              \
    DSR8O(b[0], bV, 0);    DSR8O(b[1], bV, 1024);                              \
    DSR8O(b[2], bV, 2048); DSR8O(b[3], bV, 3072);                              \
    DSR8O(b[4], bV, 4096); DSR8O(b[5], bV, 5120);                              \
    DSR8O(b[6], bV, 6144); DSR8O(b[7], bV, 7168);                              \
    STAGE_B(s_ + 1, 0, BW_); STAGE_B(s_ + 1, 1, BW_);                          \
    STAGE_A(s_ + 2, 0, AW_); STAGE_A(s_ + 2, 1, AW_);                          \
    STAGE_A(s_ + 2, 2, AW_); STAGE_A(s_ + 2, 3, AW_);                          \
    __builtin_amdgcn_s_setprio(1);                                             \
    LGK(7); CL4(0, 0); LGK(6); CL4(1, 1); LGK(5); CL4(2, 2); LGK(4); CL4(3, 3);\
    LGK(3); CL4(4, 4); LGK(2); CL4(5, 5); LGK(1); CL4(6, 6); LGK(0); CL4(7, 7);\
    __builtin_amdgcn_s_setprio(0);                                             \
    __builtin_amdgcn_sched_barrier(0);                                         \
    if ((TM_) == 0) asm volatile("s_waitcnt vmcnt(4)" ::: "memory");           \
    __builtin_amdgcn_s_barrier();                                              \
} while (0)

__global__ __launch_bounds__(256, 2) void argmin_mfma(
    const ushort* __restrict__ zh, const ushort* __restrict__ eh,
    const float* __restrict__ enorm, unsigned long long* __restrict__ best)
{
    // ushort-indexed: A bufs x3 @ 0/8192/16384 ([256][32] each),
    // B bufs x2 @ 24576/28672 ([128][32]).  32768 ushorts = 64 KiB.
    __shared__ __align__(16) ushort lds[32768];

    const int t = threadIdx.x;
    const int w = t >> 6, lane = t & 63;
    const int quad = lane >> 4, l15 = lane & 15;

    // XCD swizzle (bijective, 512 blocks): ns = xcd -> each XCD's 64
    // resident blocks share one 1 MB B-panel in its L2.
    const int d = blockIdx.x;
    const int xcd = d & 7;
    const int ns = xcd;
    const int mt = d >> 3;                    // [0,64)
    const int m0 = mt * 256;
    const int nsN = ns * (NTPB * BN);         // 1024 * ns

    const int wrow = w * 64;                  // wave row base in A tile

    // staging lane geometry (pre-swizzled global source, linear LDS dest)
    const int lr = lane >> 2, lc = lane & 3;
    const int clog = lc ^ (lr & 3);
    const int soff = lr * DIMS + clog * 8;
    const ushort* zA = zh + (size_t)m0 * DIMS;
    const float* enormg = enorm + nsN;

    // frag-read physical chunk offset (ushorts): (quad ^ (l15&3)) * 8
    const int pxo = (quad ^ (l15 & 3)) * 8;
    const int aro = (wrow + l15) * 32;
    const int bro = l15 * 32;
    const unsigned ldsb = (unsigned)(size_t)AS3(&lds[0]);

    floatx4 acc[4][8];
    #pragma unroll
    for (int mi = 0; mi < 4; mi++)
        #pragma unroll
        for (int nj = 0; nj < 8; nj++)
            acc[mi][nj] = (floatx4){0.f, 0.f, 0.f, 0.f};

    float bs[16];
    int   bn_[16];
    #pragma unroll
    for (int k = 0; k < 16; k++) { bs[k] = 3.4e38f; bn_[k] = 0; }

    // prologue: A(0)->buf0 (4), B(0)->B0 (2), A(1)->buf1 (4); vmcnt(4)
    // retires A(0)+B(0), A(1) rides; barrier
    STAGE_A(0, 0, 0u); STAGE_A(0, 1, 0u); STAGE_A(0, 2, 0u); STAGE_A(0, 3, 0u);
    STAGE_B(0, 0, 24576u); STAGE_B(0, 1, 24576u);
    STAGE_A(1, 0, 8192u); STAGE_A(1, 1, 8192u);
    STAGE_A(1, 2, 8192u); STAGE_A(1, 3, 8192u);
    asm volatile("s_waitcnt vmcnt(4)" ::: "memory");
    __builtin_amdgcn_s_barrier();

    // A-buffer rotation: step s reads aR (= buf s%3), stages A(s+2) into
    // aW (= buf (s+2)%3); rotate (aR,aN,aW) <- (aN,aW,aR) each step.
    unsigned aR = 0u, aN = 8192u, aW = 16384u;

    for (int sp = 0; sp < NSTEPS; sp += 2) {
        STEP(sp, aR, 24576u, aW, 28672u, 0);
        { unsigned t_ = aR; aR = aN; aN = aW; aW = t_; }
        STEP(sp + 1, aR, 28672u, aW, 24576u, (sp == NSTEPS - 2) ? 2 : 0);
        { unsigned t_ = aR; aR = aN; aN = aW; aW = t_; }

        if ((sp & 15) == 14) {
            // n-tile finished: fold scores into running best, reset acc.
            // C/D frag: col = l15 (n), row = quad*4 + r (m).
            // enorm via global (L2-hot); vmcnt(0) also retires staging
            // loads that are ~1 step old -> drain cost ~= enorm latency.
            const int nt = sp >> 4;
            const int eb = nt * BN + l15;
            const int nbase = nsN + eb;
            float en[8];
            #pragma unroll
            for (int nj = 0; nj < 8; nj++) {
                const float* ep_ = enormg + eb + nj * 16;
                asm volatile("global_load_dword %0, %1, off"
                             : "=v"(en[nj]) : "v"(ep_));
            }
            asm volatile("s_waitcnt vmcnt(0)" ::: "memory");
            __builtin_amdgcn_sched_barrier(0);
            #pragma unroll
            for (int nj = 0; nj < 8; nj++) {          // nj asc = n asc
                const int n = nbase + nj * 16;
                #pragma unroll
                for (int mi = 0; mi < 4; mi++) {
                    #pragma unroll
                    for (int r = 0; r < 4; r++) {
                        const int k = mi * 4 + r;
                        const float sc = fmaf(-2.0f, acc[mi][nj][r], en[nj]);
                        if (sc < bs[k]) { bs[k] = sc; bn_[k] = n; }
                    }
                    acc[mi][nj] = (floatx4){0.f, 0.f, 0.f, 0.f};
                }
            }
        }
    }

    // drain tail staging gloads before epilogue/endpgm (once, cheap)
    asm volatile("s_waitcnt vmcnt(0)" ::: "memory");

    // once per block: pack, shfl-min over l15 group, atomicMin across splits
    #pragma unroll
    for (int mi = 0; mi < 4; mi++)
        #pragma unroll
        for (int r = 0; r < 4; r++) {
            const int k = mi * 4 + r;
            unsigned su = __builtin_bit_cast(unsigned, bs[k]);
            su = (su & 0x80000000u) ? ~su : (su | 0x80000000u);  // order-preserving
            unsigned long long key = ((unsigned long long)su << 32) | (unsigned)bn_[k];
            #pragma unroll
            for (int off = 1; off < 16; off <<= 1) {
                unsigned long long o = __shfl_xor(key, off, 64);
                key = (o < key) ? o : key;
            }
            if (l15 == 0) atomicMin(&best[m0 + wrow + mi * 16 + quad * 4 + r], key);
        }
}

// one block per 32 rows: idx from packed keys, gather z_q, loss + idx stats;
// last block to finish runs the finalize.
__global__ __launch_bounds__(256) void gather_loss_kernel(
    const float* __restrict__ z, const float* __restrict__ emb,
    const unsigned long long* __restrict__ best,
    float* __restrict__ out, double* __restrict__ sums, unsigned* __restrict__ counter)
{
    __shared__ int sIdx[32];
    __shared__ double red[4];
    const int t = threadIdx.x;
    const int row0 = blockIdx.x * 32;
    double myIdxSum = 0.0, myIdxSq = 0.0;
    if (t < 32) {
        int row = row0 + t;
        int idx = (int)(unsigned)(best[row] & 0xFFFFFFFFULL);
        sIdx[t] = idx;
        out[IDX_OFF + row] = (float)idx;
        myIdxSum = (double)idx;
        myIdxSq = (double)idx * (double)idx;
    }
    __syncthreads();
    double acc = 0.0;
    #pragma unroll 4
    for (int i = 0; i < 16; i++) {
        int e = i * 1024 + t * 4;        // 32 rows x 512 = 16384 elems per block
        int rl = e >> 9;
        int c = e & 511;
        int idx = sIdx[rl];
        float4 zv = *(const float4*)(z + (size_t)(row0 + rl) * DIMS + c);
        float4 ev = *(const float4*)(emb + (size_t)idx * DIMS + c);
        *(float4*)(out + (size_t)(row0 + rl) * DIMS + c) = ev;  // z_q_st value == z_q
        float dx = zv.x - ev.x, dy = zv.y - ev.y;
        float dz = zv.z - ev.z, dw = zv.w - ev.w;
        acc += (double)(dx * dx + dy * dy) + (double)(dz * dz + dw * dw);
    }
    const int lane = t & 63, wv = t >> 6;
    #pragma unroll
    for (int off = 32; off > 0; off >>= 1) {
        acc      += __shfl_down(acc, off, 64);
        myIdxSum += __shfl_down(myIdxSum, off, 64);
        myIdxSq  += __shfl_down(myIdxSq, off, 64);
    }
    if (lane == 0) red[wv] = acc;
    __syncthreads();
    if (t == 0) {
        double tot = red[0] + red[1] + red[2] + red[3];
        atomicAdd(&sums[0], tot);
        atomicAdd(&sums[1], myIdxSum);   // wave 0 held all idx stats
        atomicAdd(&sums[2], myIdxSq);
        __threadfence();
        unsigned old = atomicAdd(counter, 1u);
        if (old == gridDim.x - 1) {
            __threadfence();
            double s0 = atomicAdd(&sums[0], 0.0);
            double s1 = atomicAdd(&sums[1], 0.0);
            double s2 = atomicAdd(&sums[2], 0.0);
            out[LOSS_OFF] = (float)(1.25 * s0 / (double)((size_t)BT * DIMS));
            double m = s1 / (double)BT;
            out[V_OFF] = (float)(s2 / (double)BT - m * m);
        }
    }
}

extern "C" void kernel_launch(void* const* d_in, const int* in_sizes, int n_in,
                              void* d_out, int out_size, void* d_ws, size_t ws_size,
                              hipStream_t stream) {
    const float* z = (const float*)d_in[0];
    const float* emb = (const float*)d_in[1];
    float* out = (float*)d_out;
    char* ws = (char*)d_ws;
    unsigned long long* best = (unsigned long long*)(ws + BEST_OFF);
    float* enorm  = (float*)(ws + ENORM_OFF);
    double* sums  = (double*)(ws + SUMS_OFF);
    unsigned* counter = (unsigned*)(ws + CNT_OFF);

    // bf16 scratch in the z_q region of out (fully overwritten by gather at the end)
    ushort* zh = (ushort*)out;
    ushort* ehh = zh + (size_t)BT * DIMS;

    hipLaunchKernelGGL(prep_kernel, dim3(NE / 4 + BT / 4), dim3(256), 0, stream,
                       z, emb, zh, ehh, enorm, best, sums, counter);
    hipLaunchKernelGGL(argmin_mfma, dim3(512), dim3(256), 0, stream,
                       zh, ehh, enorm, best);
    hipLaunchKernelGGL(gather_loss_kernel, dim3(BT / 32), dim3(256), 0, stream,
                       z, emb, best, out, sums, counter);
}